// Round 6
// baseline (539.475 us; speedup 1.0000x reference)
//
#include <hip/hip_runtime.h>
#include <cfloat>

#define N_NODES 50000
#define N_EDGES 800000
#define N_GRAPHS 64
#define DEG_BUCKETS 64
#define SCAN_NB ((N_NODES + 255) / 256)   // 196

// CSR binning parameters
#define BUK_SHIFT 8                        // 256 nodes per bucket
#define NBUK ((N_NODES + 255) / 256)       // 196 buckets
#define CHUNK 4096                         // edges per binscat block
#define CAP 6144                           // LDS csrc staging capacity (mean region = 4096)

typedef _Float16 half8 __attribute__((ext_vector_type(8)));
typedef _Float16 half4 __attribute__((ext_vector_type(4)));
typedef _Float16 half2t __attribute__((ext_vector_type(2)));
typedef _Float16 f16x8 __attribute__((ext_vector_type(8)));
typedef float f32x4 __attribute__((ext_vector_type(4)));

// ---------------- CSR build: bucket histogram ----------------

__global__ __launch_bounds__(256) void bucket_hist_kernel(const int* __restrict__ dst,
                                                          int* __restrict__ bhist, int n) {
    __shared__ int lh[NBUK];
    int t = threadIdx.x;
    if (t < NBUK) lh[t] = 0;
    __syncthreads();
    int i0 = blockIdx.x * 1024;
#pragma unroll
    for (int j = 0; j < 4; ++j) {
        int i = i0 + j * 256 + t;
        if (i < n) atomicAdd(&lh[dst[i] >> BUK_SHIFT], 1);
    }
    __syncthreads();
    if (t < NBUK && lh[t]) atomicAdd(&bhist[t], lh[t]);
}

// single block: scan 196 bucket counts -> bbase (exclusive, +total), init bcur
__global__ __launch_bounds__(256) void bucket_scan_kernel(const int* __restrict__ bhist,
                                                          int* __restrict__ bbase,
                                                          int* __restrict__ bcur) {
    __shared__ int sm[256];
    int t = threadIdx.x;
    int v = (t < NBUK) ? bhist[t] : 0;
    sm[t] = v;
    __syncthreads();
    for (int off = 1; off < 256; off <<= 1) {
        int x = (t >= off) ? sm[t - off] : 0;
        __syncthreads();
        sm[t] += x;
        __syncthreads();
    }
    int excl = sm[t] - v;
    if (t < NBUK) { bbase[t] = excl; bcur[t] = excl; }
    if (t == 255) bbase[NBUK] = sm[255];
}

// ---------------- binscat: LDS-staged bucket append (coalesced flushes) ----------------

__global__ __launch_bounds__(256) void binscat_kernel(const int* __restrict__ src,
        const int* __restrict__ dst, int* __restrict__ bcur,
        int2* __restrict__ ebuf, int n) {
    __shared__ int2 staged[CHUNK];
    __shared__ int lh[NBUK], lbase[NBUK], lpos[NBUK], gpos[NBUK];
    __shared__ int ssc[256];
    int t = threadIdx.x;
    int e0 = blockIdx.x * CHUNK;
    int len = n - e0; if (len > CHUNK) len = CHUNK; if (len < 0) len = 0;
    if (t < NBUK) { lh[t] = 0; lpos[t] = 0; }
    __syncthreads();
    int s[16], d[16];
#pragma unroll
    for (int j = 0; j < 16; ++j) {
        int i = j * 256 + t;
        if (i < len) {
            s[j] = src[e0 + i];
            d[j] = dst[e0 + i];
            atomicAdd(&lh[d[j] >> BUK_SHIFT], 1);
        } else d[j] = -1;
    }
    __syncthreads();
    // block scan of lh (NBUK <= 256)
    int v = (t < NBUK) ? lh[t] : 0;
    ssc[t] = v;
    __syncthreads();
    for (int off = 1; off < 256; off <<= 1) {
        int x = (t >= off) ? ssc[t - off] : 0;
        __syncthreads();
        ssc[t] += x;
        __syncthreads();
    }
    if (t < NBUK) {
        lbase[t] = ssc[t] - v;
        gpos[t] = v ? atomicAdd(&bcur[t], v) : 0;
    }
    __syncthreads();
#pragma unroll
    for (int j = 0; j < 16; ++j) {
        if (d[j] >= 0) {
            int b = d[j] >> BUK_SHIFT;
            int slot = lbase[b] + atomicAdd(&lpos[b], 1);
            staged[slot] = make_int2(s[j], d[j]);
        }
    }
    __syncthreads();
    // flush: bucket segments are contiguous in staged AND in ebuf -> coalesced runs
    for (int i = t; i < len; i += 256) {
        int2 p = staged[i];
        int b = p.y >> BUK_SHIFT;
        ebuf[gpos[b] + (i - lbase[b])] = p;
    }
}

// ---------------- csr_final: per-bucket CSR segment in LDS, coalesced out ----------------
// Emits rowptr, csrc, deg, and degree-histogram (for LPT perm).

__global__ __launch_bounds__(256) void csr_final_kernel(const int2* __restrict__ ebuf,
        const int* __restrict__ bbase, int* __restrict__ rowptr, int* __restrict__ csrc,
        int* __restrict__ deg, int* __restrict__ dhist, int n_nodes, int n_edges) {
    __shared__ int lcnt[256], lbs[256], lpos[256], ssc[256];
    __shared__ int lh64[DEG_BUCKETS];
    __shared__ int buf[CAP];
    int b = blockIdx.x, t = threadIdx.x;
    int nstart = b << BUK_SHIFT;
    int nodes = n_nodes - nstart; if (nodes > 256) nodes = 256;
    int r0 = bbase[b], r1 = bbase[b + 1];
    int len = r1 - r0;
    lcnt[t] = 0;
    lpos[t] = 0;
    if (t < DEG_BUCKETS) lh64[t] = 0;
    __syncthreads();
    for (int i = t; i < len; i += 256)
        atomicAdd(&lcnt[ebuf[r0 + i].y - nstart], 1);
    __syncthreads();
    int v = lcnt[t];
    ssc[t] = v;
    __syncthreads();
    for (int off = 1; off < 256; off <<= 1) {
        int x = (t >= off) ? ssc[t - off] : 0;
        __syncthreads();
        ssc[t] += x;
        __syncthreads();
    }
    lbs[t] = ssc[t] - v;                      // exclusive local base
    if (t < nodes) {
        rowptr[nstart + t] = r0 + lbs[t];
        deg[nstart + t] = v;
        int dd = (v > DEG_BUCKETS - 1) ? DEG_BUCKETS - 1 : v;
        atomicAdd(&lh64[dd], 1);
    }
    if (b == NBUK - 1 && t == 0) rowptr[n_nodes] = n_edges;
    __syncthreads();
    if (t < DEG_BUCKETS && lh64[t]) atomicAdd(&dhist[t], lh64[t]);
    if (len <= CAP) {
        for (int i = t; i < len; i += 256) {
            int2 p = ebuf[r0 + i];
            int dn = p.y - nstart;
            int pos = lbs[dn] + atomicAdd(&lpos[dn], 1);
            buf[pos] = p.x;
        }
        __syncthreads();
        for (int i = t; i < len; i += 256) csrc[r0 + i] = buf[i];
    } else {
        // freak-bucket fallback: direct global scatter (correct, slower)
        for (int i = t; i < len; i += 256) {
            int2 p = ebuf[r0 + i];
            int dn = p.y - nstart;
            int pos = lbs[dn] + atomicAdd(&lpos[dn], 1);
            csrc[r0 + pos] = p.x;
        }
    }
}

// ---------------- degree-bucket scan + LPT perm ----------------

__global__ void dscan_kernel(const int* __restrict__ dhist, int* __restrict__ dcur) {
    int t = threadIdx.x;  // 64
    int dv = dhist[t];
    int incl = dv;
    for (int off = 1; off < 64; off <<= 1) {
        int x = __shfl_up(incl, off, 64);
        if (t >= off) incl += x;
    }
    dcur[t] = incl - dv;
}

__global__ __launch_bounds__(256) void perm_kernel(const int* __restrict__ deg,
        int* __restrict__ dcur, int* __restrict__ perm, int n) {
    __shared__ int lh[DEG_BUCKETS], lbase[DEG_BUCKETS];
    int t = threadIdx.x;
    int i = blockIdx.x * 256 + t;
    if (t < DEG_BUCKETS) lh[t] = 0;
    __syncthreads();
    int d = 0, loc = 0;
    bool valid = (i < n);
    if (valid) {
        int v = deg[i];
        d = (v > DEG_BUCKETS - 1) ? DEG_BUCKETS - 1 : v;
        loc = atomicAdd(&lh[d], 1);
    }
    __syncthreads();
    if (t < DEG_BUCKETS) lbase[t] = lh[t] ? atomicAdd(&dcur[t], lh[t]) : 0;
    __syncthreads();
    if (valid) perm[lbase[d] + loc] = i;
}

// ---------------- MFMA dual GEMM: [xl|xr] = h @ [Wl|Wr], fp16 out, f32/f16 in ----------------

template<typename TIN, int DIN, int DOUT>
__global__ __launch_bounds__(256) void mfma_gemm_kernel(const TIN* __restrict__ h,
        const float* __restrict__ Wl, const float* __restrict__ Wr,
        _Float16* __restrict__ xl, _Float16* __restrict__ xr, int n) {
    constexpr int NOUT = 2 * DOUT;
    constexpr int BM = 64;
    constexpr int NCH = DIN / 8;                      // 16B chunks per LDS row
    constexpr int XORM = (NCH < 8 ? NCH : 8) - 1;
    constexpr int NT = NOUT / 16;
    static_assert(DIN % 32 == 0 && DOUT % 16 == 0, "shape");
    __shared__ _Float16 sA[BM * DIN];
    __shared__ _Float16 sW[NOUT * DIN];               // W^T: [n][k]
    int tid = threadIdx.x;
    int r0 = blockIdx.x * BM;

    // stage W^T fp16 (swizzled); W is [DIN][DOUT] row-major fp32
    for (int i = tid; i < DIN * DOUT; i += 256) {
        int k = i / DOUT, c = i % DOUT;
        sW[c * DIN + (k ^ ((c & XORM) << 3))] = (_Float16)Wl[i];
        int nr = DOUT + c;
        sW[nr * DIN + (k ^ ((nr & XORM) << 3))] = (_Float16)Wr[i];
    }
    // stage A fp16 (swizzled)
    if constexpr (sizeof(TIN) == 4) {
        constexpr int DQ = DIN / 4;
        for (int i = tid; i < BM * DQ; i += 256) {
            int row = i / DQ, kq = (i % DQ) * 4;
            float4 v = (r0 + row < n) ? *(const float4*)(h + (size_t)(r0 + row) * DIN + kq)
                                      : make_float4(0.f, 0.f, 0.f, 0.f);
            half4 hv = {(_Float16)v.x, (_Float16)v.y, (_Float16)v.z, (_Float16)v.w};
            *(half4*)(sA + row * DIN + (kq ^ ((row & XORM) << 3))) = hv;
        }
    } else {
        constexpr int D8 = DIN / 8;
        for (int i = tid; i < BM * D8; i += 256) {
            int row = i / D8, k8 = (i % D8) * 8;
            half8 hv;
            if (r0 + row < n) hv = *(const half8*)(h + (size_t)(r0 + row) * DIN + k8);
            else hv = half8{0, 0, 0, 0, 0, 0, 0, 0};
            *(half8*)(sA + row * DIN + (k8 ^ ((row & XORM) << 3))) = hv;
        }
    }
    __syncthreads();

    int w = tid >> 6, lane = tid & 63;
    int lrow = lane & 15, lg = lane >> 4;
    int arow = w * 16 + lrow;

    f32x4 acc[NT];
#pragma unroll
    for (int i = 0; i < NT; ++i) acc[i] = (f32x4){0.f, 0.f, 0.f, 0.f};

#pragma unroll
    for (int kk = 0; kk < DIN; kk += 32) {
        int ka = kk + lg * 8;
        f16x8 af = *(const f16x8*)(sA + arow * DIN + (ka ^ ((arow & XORM) << 3)));
#pragma unroll
        for (int nt = 0; nt < NT; ++nt) {
            int bcol = nt * 16 + lrow;
            f16x8 bf = *(const f16x8*)(sW + bcol * DIN + (ka ^ ((bcol & XORM) << 3)));
            acc[nt] = __builtin_amdgcn_mfma_f32_16x16x32_f16(af, bf, acc[nt], 0, 0, 0);
        }
    }

    int orow0 = r0 + w * 16 + lg * 4;
#pragma unroll
    for (int nt = 0; nt < NT; ++nt) {
        int c = nt * 16 + lrow;
        _Float16* obase = (c < DOUT) ? xl : xr;
        int cc = (c < DOUT) ? c : c - DOUT;
#pragma unroll
        for (int r = 0; r < 4; ++r) {
            int row = orow0 + r;
            if (row < n) obase[(size_t)row * DOUT + cc] = (_Float16)acc[nt][r];
        }
    }
}

// ---------------- fused per-node GATv2 softmax-aggregate (fp16, packed dot2) ----------------
// Score path in packed fp16: t = xl+xr via v_pk_add_f16, |t| via bit-mask,
// attention dot via v_dot2_f32_f16 (f32 accumulate). Aggregation stays f32.
// POOL=true: fuse global-max-pool -> atomicMax into encoded pool (no row write).

union H8 {
    half8 v;
    half2t h2[4];
    unsigned int u[4];
};

__device__ __forceinline__ unsigned int enc_f32(float f) {
    unsigned int b = __float_as_uint(f);
    return (b & 0x80000000u) ? ~b : (b | 0x80000000u);
}
__device__ __forceinline__ float dec_f32(unsigned int u) {
    unsigned int b = (u & 0x80000000u) ? (u ^ 0x80000000u) : ~u;
    return __uint_as_float(b);
}

template<int DOUT, int U, bool LEAKY, bool POOL>
__global__ __launch_bounds__(256) void edge_kernel(
        const _Float16* __restrict__ xl, const _Float16* __restrict__ xr,
        const float* __restrict__ avec, const float* __restrict__ bias,
        const int* __restrict__ rowptr, const int* __restrict__ csrc,
        const int* __restrict__ perm,
        _Float16* __restrict__ out,
        const int* __restrict__ batchp, unsigned int* __restrict__ gout, int n) {
    constexpr int LANES = DOUT / 8;              // 4 / 8 / 16
    constexpr int NPW = 64 / LANES;              // nodes per wave
    int wid = (blockIdx.x * blockDim.x + threadIdx.x) >> 6;
    int lane = threadIdx.x & 63;
    int group = lane / LANES;
    int gl = lane % LANES;
    int gnode = wid * NPW + group;
    if (gnode >= n) return;
    int node = perm[n - 1 - gnode];              // descending degree (LPT)

    constexpr float L2E = 1.44269504f;
    const float* ap = avec + 8 * gl;
    half2t a6h[4], a4h[4];
#pragma unroll
    for (int j = 0; j < 4; ++j) {
        float x0 = 0.6f * L2E * ap[2 * j], x1 = 0.6f * L2E * ap[2 * j + 1];
        a6h[j] = half2t{(_Float16)x0, (_Float16)x1};
        float y0 = 0.4f * L2E * ap[2 * j], y1 = 0.4f * L2E * ap[2 * j + 1];
        a4h[j] = half2t{(_Float16)y0, (_Float16)y1};
    }

    int nbase = node * DOUT + 8 * gl;
    half8 xrh = *(const half8*)(xr + nbase);
    const _Float16* xlg = xl + 8 * gl;

    float acc[8] = {};
    float denom = 0.f;
    int e0 = rowptr[node], e1 = rowptr[node + 1];

    for (int p = e0; p < e1; p += U) {
        int sidx[U];
#pragma unroll
        for (int u = 0; u < U; ++u) {
            int q = p + u;
            sidx[u] = (q < e1) ? csrc[q] : -1;
        }
        half8 xlv[U];
#pragma unroll
        for (int u = 0; u < U; ++u) {
            int s = (sidx[u] >= 0) ? sidx[u] : 0;
            xlv[u] = *(const half8*)(xlg + (size_t)s * DOUT);
        }
        float part[U];
#pragma unroll
        for (int u = 0; u < U; ++u) {
            H8 t, ta;
            t.v = xlv[u] + xrh;                      // v_pk_add_f16
#pragma unroll
            for (int j = 0; j < 4; ++j) ta.u[j] = t.u[j] & 0x7fff7fffu;
            float pu = 0.f;
#pragma unroll
            for (int j = 0; j < 4; ++j) {
                pu = __builtin_amdgcn_fdot2(a6h[j], t.h2[j], pu, false);
                pu = __builtin_amdgcn_fdot2(a4h[j], ta.h2[j], pu, false);
            }
            part[u] = pu;
        }
#pragma unroll
        for (int mask = LANES / 2; mask >= 1; mask >>= 1)
#pragma unroll
            for (int u = 0; u < U; ++u)
                part[u] += __shfl_xor(part[u], mask, 64);
#pragma unroll
        for (int u = 0; u < U; ++u) {
            float w = __builtin_exp2f(part[u]);   // v_exp_f32
            w = (sidx[u] >= 0) ? w : 0.f;
            denom += w;
#pragma unroll
            for (int i = 0; i < 8; ++i)
                acc[i] += w * (float)xlv[u][i];
        }
    }
    float inv = 1.f / (denom + 1e-16f);
    const float* bp = bias + 8 * gl;
    float o[8];
#pragma unroll
    for (int i = 0; i < 8; ++i) {
        float v = acc[i] * inv + bp[i];
        if (LEAKY) v = (v > 0.f) ? v : 0.01f * v;
        o[i] = v;
    }
    if (POOL) {
        int g = batchp[node];
        unsigned int* gp = gout + (g << 7) + 8 * gl;
#pragma unroll
        for (int i = 0; i < 8; ++i) atomicMax(gp + i, enc_f32(o[i]));
    } else {
        half8 ov;
#pragma unroll
        for (int i = 0; i < 8; ++i) ov[i] = (_Float16)o[i];
        *(half8*)(out + nbase) = ov;
    }
}

// ---------------- MLP head: column x k-split parallel kernels ----------------

__global__ __launch_bounds__(256) void mlp1_kernel(const unsigned int* __restrict__ gpool,
        const float* __restrict__ w1, const float* __restrict__ b1,
        float* __restrict__ act1) {
    __shared__ float A[128];
    int g = blockIdx.x >> 2, chunk = blockIdx.x & 3;
    int t = threadIdx.x;
    if (t < 128) A[t] = dec_f32(gpool[g * 128 + t]);
    __syncthreads();
    int c = chunk * 256 + t;
    float a0 = b1[c], a1 = 0.f;
#pragma unroll 4
    for (int k = 0; k < 128; k += 2) {
        a0 += A[k] * w1[k * 1024 + c];
        a1 += A[k + 1] * w1[(k + 1) * 1024 + c];
    }
    act1[g * 1024 + c] = fmaxf(a0 + a1, 0.f);
}

template<int DIN, int DOUT>
__global__ __launch_bounds__(256) void mlp_mid_kernel(const float* __restrict__ actin,
        const float* __restrict__ w, const float* __restrict__ b,
        float* __restrict__ actout) {
    constexpr int CHUNKS = DOUT / 64;
    constexpr int KQ = DIN / 4;                 // k per split
    __shared__ float A[DIN];
    __shared__ float partial[4][64];
    int g = blockIdx.x / CHUNKS, chunk = blockIdx.x % CHUNKS;
    int t = threadIdx.x;
    for (int i = t; i < DIN; i += 256) A[i] = actin[g * DIN + i];
    __syncthreads();
    int c = chunk * 64 + (t & 63);
    int q = t >> 6;
    const float* wp = w + c + (size_t)q * KQ * DOUT;
    const float* ap = A + q * KQ;
    float a0 = 0.f, a1 = 0.f;
#pragma unroll 4
    for (int k = 0; k < KQ; k += 2) {
        a0 += ap[k] * wp[k * DOUT];
        a1 += ap[k + 1] * wp[(k + 1) * DOUT];
    }
    partial[q][t & 63] = a0 + a1;
    __syncthreads();
    if (t < 64) {
        float s = partial[0][t] + partial[1][t] + partial[2][t] + partial[3][t] + b[c];
        actout[g * DOUT + chunk * 64 + t] = fmaxf(s, 0.f);
    }
}

__global__ __launch_bounds__(128) void mlp45_kernel(const float* __restrict__ act3,
        const float* __restrict__ w4, const float* __restrict__ b4,
        const float* __restrict__ w5, const float* __restrict__ b5,
        float* __restrict__ out) {
    __shared__ float C[128], D[32];
    int g = blockIdx.x, t = threadIdx.x;
    if (t < 128) C[t] = act3[g * 128 + t];
    __syncthreads();
    if (t < 32) {
        float acc = b4[t];
#pragma unroll 4
        for (int k = 0; k < 128; ++k) acc += C[k] * w4[k * 32 + t];
        D[t] = fmaxf(acc, 0.f);
    }
    __syncthreads();
    if (t < 4) {
        float acc = b5[t];
#pragma unroll
        for (int k = 0; k < 32; ++k) acc += D[k] * w5[k * 4 + t];
        out[g * 4 + t] = acc;
    }
}

// ---------------- host launch ----------------

extern "C" void kernel_launch(void* const* d_in, const int* in_sizes, int n_in,
                              void* d_out, int out_size, void* d_ws, size_t ws_size,
                              hipStream_t stream) {
    const float* x     = (const float*)d_in[0];
    const int*   ei    = (const int*)d_in[1];
    const int*   batch = (const int*)d_in[2];
    const int*   src   = ei;
    const int*   dst   = ei + N_EDGES;
    const float* Wl1 = (const float*)d_in[3];
    const float* Wr1 = (const float*)d_in[4];
    const float* a1  = (const float*)d_in[5];
    const float* b1  = (const float*)d_in[6];
    const float* Wl2 = (const float*)d_in[7];
    const float* Wr2 = (const float*)d_in[8];
    const float* a2  = (const float*)d_in[9];
    const float* b2  = (const float*)d_in[10];
    const float* Wl3 = (const float*)d_in[11];
    const float* Wr3 = (const float*)d_in[12];
    const float* a3  = (const float*)d_in[13];
    const float* b3  = (const float*)d_in[14];
    const float* mw1 = (const float*)d_in[15];
    const float* mb1 = (const float*)d_in[16];
    const float* mw2 = (const float*)d_in[17];
    const float* mb2 = (const float*)d_in[18];
    const float* mw3 = (const float*)d_in[19];
    const float* mb3 = (const float*)d_in[20];
    const float* mw4 = (const float*)d_in[21];
    const float* mb4 = (const float*)d_in[22];
    const float* mw5 = (const float*)d_in[23];
    const float* mb5 = (const float*)d_in[24];

    char* ws = (char*)d_ws;
    size_t off = 0;
    auto alloc = [&](size_t bytes) -> void* {
        void* p = ws + off;
        off = (off + bytes + 255) & ~(size_t)255;
        return p;
    };
    // zero-init region: bhist, dhist, pool contiguous -> single memset
    int*   bhist  = (int*)alloc(NBUK * 4);
    int*   dhist  = (int*)alloc(DEG_BUCKETS * 4);
    unsigned int* pool = (unsigned int*)alloc(N_GRAPHS * 128 * 4);
    size_t zero_bytes = off;   // covers bhist..pool (0 == encoded -inf for pool)
    int*   bbase  = (int*)alloc((NBUK + 1) * 4);
    int*   bcur   = (int*)alloc(NBUK * 4);
    int*   rowptr = (int*)alloc((N_NODES + 1) * 4);
    int*   csrc   = (int*)alloc(N_EDGES * 4);
    int2*  ebuf   = (int2*)alloc((size_t)N_EDGES * 8);
    _Float16* xl  = (_Float16*)alloc((size_t)N_NODES * 128 * 2);
    _Float16* xr  = (_Float16*)alloc((size_t)N_NODES * 128 * 2);
    _Float16* hA  = (_Float16*)alloc((size_t)N_NODES * 128 * 2);
    _Float16* hB  = (_Float16*)alloc((size_t)N_NODES * 128 * 2);
    int*   dcur   = (int*)alloc(DEG_BUCKETS * 4);
    int*   perm   = (int*)alloc(N_NODES * 4);
    int*   deg    = (int*)alloc(N_NODES * 4);
    float* act1   = (float*)alloc(N_GRAPHS * 1024 * 4);
    float* act2   = (float*)alloc(N_GRAPHS * 512 * 4);
    float* act3   = (float*)alloc(N_GRAPHS * 128 * 4);

    hipMemsetAsync(bhist, 0, zero_bytes, stream);
    bucket_hist_kernel<<<(N_EDGES + 1023) / 1024, 256, 0, stream>>>(dst, bhist, N_EDGES);
    bucket_scan_kernel<<<1, 256, 0, stream>>>(bhist, bbase, bcur);
    binscat_kernel<<<(N_EDGES + CHUNK - 1) / CHUNK, 256, 0, stream>>>(src, dst, bcur, ebuf, N_EDGES);
    csr_final_kernel<<<NBUK, 256, 0, stream>>>(ebuf, bbase, rowptr, csrc, deg, dhist, N_NODES, N_EDGES);
    dscan_kernel<<<1, 64, 0, stream>>>(dhist, dcur);
    perm_kernel<<<SCAN_NB, 256, 0, stream>>>(deg, dcur, perm, N_NODES);

    auto egrid = [](int npw) {
        int waves = (N_NODES + npw - 1) / npw;
        return (waves + 3) / 4;
    };
    const int gblocks = (N_NODES + 63) / 64;   // 782

    // Layer 1: 128 -> 32 (MFMA dual GEMM, f32 in); edge NPW=16 (LANES=4), U=16, fp16 out
    mfma_gemm_kernel<float, 128, 32><<<gblocks, 256, 0, stream>>>(x, Wl1, Wr1, xl, xr, N_NODES);
    edge_kernel<32, 16, true, false><<<egrid(16), 256, 0, stream>>>(xl, xr, a1, b1, rowptr, csrc, perm, hB, nullptr, nullptr, N_NODES);
    // Layer 2: 32 -> 64 (MFMA, f16 in); edge NPW=8 (LANES=8), U=16, fp16 out
    mfma_gemm_kernel<_Float16, 32, 64><<<gblocks, 256, 0, stream>>>(hB, Wl2, Wr2, xl, xr, N_NODES);
    edge_kernel<64, 16, true, false><<<egrid(8), 256, 0, stream>>>(xl, xr, a2, b2, rowptr, csrc, perm, hA, nullptr, nullptr, N_NODES);
    // Layer 3: 64 -> 128 (MFMA, f16 in); edge NPW=4 (LANES=16), U=8, fused max-pool
    mfma_gemm_kernel<_Float16, 64, 128><<<gblocks, 256, 0, stream>>>(hA, Wl3, Wr3, xl, xr, N_NODES);
    edge_kernel<128, 8, false, true><<<egrid(4), 256, 0, stream>>>(xl, xr, a3, b3, rowptr, csrc, perm, nullptr, batch, pool, N_NODES);

    mlp1_kernel<<<N_GRAPHS * 4, 256, 0, stream>>>(pool, mw1, mb1, act1);
    mlp_mid_kernel<1024, 512><<<N_GRAPHS * 8, 256, 0, stream>>>(act1, mw2, mb2, act2);
    mlp_mid_kernel<512, 128><<<N_GRAPHS * 2, 256, 0, stream>>>(act2, mw3, mb3, act3);
    mlp45_kernel<<<N_GRAPHS, 128, 0, stream>>>(act3, mw4, mb4, mw5, mb5, (float*)d_out);
}

// Round 7
// 334.103 us; speedup vs baseline: 1.6147x; 1.6147x over previous
//
#include <hip/hip_runtime.h>
#include <cfloat>

#define N_NODES 50000
#define N_EDGES 800000
#define N_GRAPHS 64
#define POOL_CHUNK 64
#define DEG_BUCKETS 64
#define SCAN_NB ((N_NODES + 255) / 256)   // 196

// CSR binning parameters
#define BUK_SHIFT 8                        // 256 nodes per bucket
#define NBUK ((N_NODES + 255) / 256)       // 196 buckets
#define CHUNK 4096                         // edges per binscat block
#define CAP 6144                           // LDS csrc staging capacity (mean region = 4096)

typedef _Float16 half8 __attribute__((ext_vector_type(8)));
typedef _Float16 half4 __attribute__((ext_vector_type(4)));
typedef _Float16 half2t __attribute__((ext_vector_type(2)));
typedef _Float16 f16x8 __attribute__((ext_vector_type(8)));
typedef float f32x4 __attribute__((ext_vector_type(4)));

// ---------------- CSR build: bucket histogram ----------------

__global__ __launch_bounds__(256) void bucket_hist_kernel(const int* __restrict__ dst,
                                                          int* __restrict__ bhist, int n) {
    __shared__ int lh[NBUK];
    int t = threadIdx.x;
    if (t < NBUK) lh[t] = 0;
    __syncthreads();
    int i0 = blockIdx.x * 1024;
#pragma unroll
    for (int j = 0; j < 4; ++j) {
        int i = i0 + j * 256 + t;
        if (i < n) atomicAdd(&lh[dst[i] >> BUK_SHIFT], 1);
    }
    __syncthreads();
    if (t < NBUK && lh[t]) atomicAdd(&bhist[t], lh[t]);
}

// single block: scan 196 bucket counts -> bbase (exclusive, +total), init bcur
__global__ __launch_bounds__(256) void bucket_scan_kernel(const int* __restrict__ bhist,
                                                          int* __restrict__ bbase,
                                                          int* __restrict__ bcur) {
    __shared__ int sm[256];
    int t = threadIdx.x;
    int v = (t < NBUK) ? bhist[t] : 0;
    sm[t] = v;
    __syncthreads();
    for (int off = 1; off < 256; off <<= 1) {
        int x = (t >= off) ? sm[t - off] : 0;
        __syncthreads();
        sm[t] += x;
        __syncthreads();
    }
    int excl = sm[t] - v;
    if (t < NBUK) { bbase[t] = excl; bcur[t] = excl; }
    if (t == 255) bbase[NBUK] = sm[255];
}

// ---------------- binscat: LDS-staged bucket append (coalesced flushes) ----------------

__global__ __launch_bounds__(256) void binscat_kernel(const int* __restrict__ src,
        const int* __restrict__ dst, int* __restrict__ bcur,
        int2* __restrict__ ebuf, int n) {
    __shared__ int2 staged[CHUNK];
    __shared__ int lh[NBUK], lbase[NBUK], lpos[NBUK], gpos[NBUK];
    __shared__ int ssc[256];
    int t = threadIdx.x;
    int e0 = blockIdx.x * CHUNK;
    int len = n - e0; if (len > CHUNK) len = CHUNK; if (len < 0) len = 0;
    if (t < NBUK) { lh[t] = 0; lpos[t] = 0; }
    __syncthreads();
    int s[16], d[16];
#pragma unroll
    for (int j = 0; j < 16; ++j) {
        int i = j * 256 + t;
        if (i < len) {
            s[j] = src[e0 + i];
            d[j] = dst[e0 + i];
            atomicAdd(&lh[d[j] >> BUK_SHIFT], 1);
        } else d[j] = -1;
    }
    __syncthreads();
    // block scan of lh (NBUK <= 256)
    int v = (t < NBUK) ? lh[t] : 0;
    ssc[t] = v;
    __syncthreads();
    for (int off = 1; off < 256; off <<= 1) {
        int x = (t >= off) ? ssc[t - off] : 0;
        __syncthreads();
        ssc[t] += x;
        __syncthreads();
    }
    if (t < NBUK) {
        lbase[t] = ssc[t] - v;
        gpos[t] = v ? atomicAdd(&bcur[t], v) : 0;
    }
    __syncthreads();
#pragma unroll
    for (int j = 0; j < 16; ++j) {
        if (d[j] >= 0) {
            int b = d[j] >> BUK_SHIFT;
            int slot = lbase[b] + atomicAdd(&lpos[b], 1);
            staged[slot] = make_int2(s[j], d[j]);
        }
    }
    __syncthreads();
    // flush: bucket segments are contiguous in staged AND in ebuf -> coalesced runs
    for (int i = t; i < len; i += 256) {
        int2 p = staged[i];
        int b = p.y >> BUK_SHIFT;
        ebuf[gpos[b] + (i - lbase[b])] = p;
    }
}

// ---------------- csr_final: per-bucket CSR segment in LDS, coalesced out ----------------
// Emits rowptr, csrc, deg, and degree-histogram (for LPT perm).

__global__ __launch_bounds__(256) void csr_final_kernel(const int2* __restrict__ ebuf,
        const int* __restrict__ bbase, int* __restrict__ rowptr, int* __restrict__ csrc,
        int* __restrict__ deg, int* __restrict__ dhist, int n_nodes, int n_edges) {
    __shared__ int lcnt[256], lbs[256], lpos[256], ssc[256];
    __shared__ int lh64[DEG_BUCKETS];
    __shared__ int buf[CAP];
    int b = blockIdx.x, t = threadIdx.x;
    int nstart = b << BUK_SHIFT;
    int nodes = n_nodes - nstart; if (nodes > 256) nodes = 256;
    int r0 = bbase[b], r1 = bbase[b + 1];
    int len = r1 - r0;
    lcnt[t] = 0;
    lpos[t] = 0;
    if (t < DEG_BUCKETS) lh64[t] = 0;
    __syncthreads();
    for (int i = t; i < len; i += 256)
        atomicAdd(&lcnt[ebuf[r0 + i].y - nstart], 1);
    __syncthreads();
    int v = lcnt[t];
    ssc[t] = v;
    __syncthreads();
    for (int off = 1; off < 256; off <<= 1) {
        int x = (t >= off) ? ssc[t - off] : 0;
        __syncthreads();
        ssc[t] += x;
        __syncthreads();
    }
    lbs[t] = ssc[t] - v;                      // exclusive local base
    if (t < nodes) {
        rowptr[nstart + t] = r0 + lbs[t];
        deg[nstart + t] = v;
        int dd = (v > DEG_BUCKETS - 1) ? DEG_BUCKETS - 1 : v;
        atomicAdd(&lh64[dd], 1);
    }
    if (b == NBUK - 1 && t == 0) rowptr[n_nodes] = n_edges;
    __syncthreads();
    if (t < DEG_BUCKETS && lh64[t]) atomicAdd(&dhist[t], lh64[t]);
    if (len <= CAP) {
        for (int i = t; i < len; i += 256) {
            int2 p = ebuf[r0 + i];
            int dn = p.y - nstart;
            int pos = lbs[dn] + atomicAdd(&lpos[dn], 1);
            buf[pos] = p.x;
        }
        __syncthreads();
        for (int i = t; i < len; i += 256) csrc[r0 + i] = buf[i];
    } else {
        // freak-bucket fallback: direct global scatter (correct, slower)
        for (int i = t; i < len; i += 256) {
            int2 p = ebuf[r0 + i];
            int dn = p.y - nstart;
            int pos = lbs[dn] + atomicAdd(&lpos[dn], 1);
            csrc[r0 + pos] = p.x;
        }
    }
}

// ---------------- degree-bucket scan + LPT perm ----------------

__global__ void dscan_kernel(const int* __restrict__ dhist, int* __restrict__ dcur) {
    int t = threadIdx.x;  // 64
    int dv = dhist[t];
    int incl = dv;
    for (int off = 1; off < 64; off <<= 1) {
        int x = __shfl_up(incl, off, 64);
        if (t >= off) incl += x;
    }
    dcur[t] = incl - dv;
}

__global__ __launch_bounds__(256) void perm_kernel(const int* __restrict__ deg,
        int* __restrict__ dcur, int* __restrict__ perm, int n) {
    __shared__ int lh[DEG_BUCKETS], lbase[DEG_BUCKETS];
    int t = threadIdx.x;
    int i = blockIdx.x * 256 + t;
    if (t < DEG_BUCKETS) lh[t] = 0;
    __syncthreads();
    int d = 0, loc = 0;
    bool valid = (i < n);
    if (valid) {
        int v = deg[i];
        d = (v > DEG_BUCKETS - 1) ? DEG_BUCKETS - 1 : v;
        loc = atomicAdd(&lh[d], 1);
    }
    __syncthreads();
    if (t < DEG_BUCKETS) lbase[t] = lh[t] ? atomicAdd(&dcur[t], lh[t]) : 0;
    __syncthreads();
    if (valid) perm[lbase[d] + loc] = i;
}

// ---------------- MFMA dual GEMM: [xl|xr] = h @ [Wl|Wr], fp16 out, f32/f16 in ----------------

template<typename TIN, int DIN, int DOUT>
__global__ __launch_bounds__(256) void mfma_gemm_kernel(const TIN* __restrict__ h,
        const float* __restrict__ Wl, const float* __restrict__ Wr,
        _Float16* __restrict__ xl, _Float16* __restrict__ xr, int n) {
    constexpr int NOUT = 2 * DOUT;
    constexpr int BM = 64;
    constexpr int NCH = DIN / 8;                      // 16B chunks per LDS row
    constexpr int XORM = (NCH < 8 ? NCH : 8) - 1;
    constexpr int NT = NOUT / 16;
    static_assert(DIN % 32 == 0 && DOUT % 16 == 0, "shape");
    __shared__ _Float16 sA[BM * DIN];
    __shared__ _Float16 sW[NOUT * DIN];               // W^T: [n][k]
    int tid = threadIdx.x;
    int r0 = blockIdx.x * BM;

    // stage W^T fp16 (swizzled); W is [DIN][DOUT] row-major fp32
    for (int i = tid; i < DIN * DOUT; i += 256) {
        int k = i / DOUT, c = i % DOUT;
        sW[c * DIN + (k ^ ((c & XORM) << 3))] = (_Float16)Wl[i];
        int nr = DOUT + c;
        sW[nr * DIN + (k ^ ((nr & XORM) << 3))] = (_Float16)Wr[i];
    }
    // stage A fp16 (swizzled)
    if constexpr (sizeof(TIN) == 4) {
        constexpr int DQ = DIN / 4;
        for (int i = tid; i < BM * DQ; i += 256) {
            int row = i / DQ, kq = (i % DQ) * 4;
            float4 v = (r0 + row < n) ? *(const float4*)(h + (size_t)(r0 + row) * DIN + kq)
                                      : make_float4(0.f, 0.f, 0.f, 0.f);
            half4 hv = {(_Float16)v.x, (_Float16)v.y, (_Float16)v.z, (_Float16)v.w};
            *(half4*)(sA + row * DIN + (kq ^ ((row & XORM) << 3))) = hv;
        }
    } else {
        constexpr int D8 = DIN / 8;
        for (int i = tid; i < BM * D8; i += 256) {
            int row = i / D8, k8 = (i % D8) * 8;
            half8 hv;
            if (r0 + row < n) hv = *(const half8*)(h + (size_t)(r0 + row) * DIN + k8);
            else hv = half8{0, 0, 0, 0, 0, 0, 0, 0};
            *(half8*)(sA + row * DIN + (k8 ^ ((row & XORM) << 3))) = hv;
        }
    }
    __syncthreads();

    int w = tid >> 6, lane = tid & 63;
    int lrow = lane & 15, lg = lane >> 4;
    int arow = w * 16 + lrow;

    f32x4 acc[NT];
#pragma unroll
    for (int i = 0; i < NT; ++i) acc[i] = (f32x4){0.f, 0.f, 0.f, 0.f};

#pragma unroll
    for (int kk = 0; kk < DIN; kk += 32) {
        int ka = kk + lg * 8;
        f16x8 af = *(const f16x8*)(sA + arow * DIN + (ka ^ ((arow & XORM) << 3)));
#pragma unroll
        for (int nt = 0; nt < NT; ++nt) {
            int bcol = nt * 16 + lrow;
            f16x8 bf = *(const f16x8*)(sW + bcol * DIN + (ka ^ ((bcol & XORM) << 3)));
            acc[nt] = __builtin_amdgcn_mfma_f32_16x16x32_f16(af, bf, acc[nt], 0, 0, 0);
        }
    }

    int orow0 = r0 + w * 16 + lg * 4;
#pragma unroll
    for (int nt = 0; nt < NT; ++nt) {
        int c = nt * 16 + lrow;
        _Float16* obase = (c < DOUT) ? xl : xr;
        int cc = (c < DOUT) ? c : c - DOUT;
#pragma unroll
        for (int r = 0; r < 4; ++r) {
            int row = orow0 + r;
            if (row < n) obase[(size_t)row * DOUT + cc] = (_Float16)acc[nt][r];
        }
    }
}

// ---------------- fused per-node GATv2 softmax-aggregate (fp16, packed dot2) ----------------
// Score path in packed fp16: t = xl+xr via v_pk_add_f16, |t| via bit-mask,
// attention dot via v_dot2_f32_f16 (f32 accumulate). Aggregation stays f32;
// output row stored fp16 (next GEMM consumes fp16 directly).

union H8 {
    half8 v;
    half2t h2[4];
    unsigned int u[4];
};

__device__ __forceinline__ unsigned int enc_f32(float f) {
    unsigned int b = __float_as_uint(f);
    return (b & 0x80000000u) ? ~b : (b | 0x80000000u);
}
__device__ __forceinline__ float dec_f32(unsigned int u) {
    unsigned int b = (u & 0x80000000u) ? (u ^ 0x80000000u) : ~u;
    return __uint_as_float(b);
}

template<int DOUT, int U, bool LEAKY>
__global__ __launch_bounds__(256) void edge_kernel(
        const _Float16* __restrict__ xl, const _Float16* __restrict__ xr,
        const float* __restrict__ avec, const float* __restrict__ bias,
        const int* __restrict__ rowptr, const int* __restrict__ csrc,
        const int* __restrict__ perm,
        _Float16* __restrict__ out, int n) {
    constexpr int LANES = DOUT / 8;              // 4 / 8 / 16
    constexpr int NPW = 64 / LANES;              // nodes per wave
    int wid = (blockIdx.x * blockDim.x + threadIdx.x) >> 6;
    int lane = threadIdx.x & 63;
    int group = lane / LANES;
    int gl = lane % LANES;
    int gnode = wid * NPW + group;
    if (gnode >= n) return;
    int node = perm[n - 1 - gnode];              // descending degree (LPT)

    constexpr float L2E = 1.44269504f;
    const float* ap = avec + 8 * gl;
    half2t a6h[4], a4h[4];
#pragma unroll
    for (int j = 0; j < 4; ++j) {
        float x0 = 0.6f * L2E * ap[2 * j], x1 = 0.6f * L2E * ap[2 * j + 1];
        a6h[j] = half2t{(_Float16)x0, (_Float16)x1};
        float y0 = 0.4f * L2E * ap[2 * j], y1 = 0.4f * L2E * ap[2 * j + 1];
        a4h[j] = half2t{(_Float16)y0, (_Float16)y1};
    }

    int nbase = node * DOUT + 8 * gl;
    half8 xrh = *(const half8*)(xr + nbase);
    const _Float16* xlg = xl + 8 * gl;

    float acc[8] = {};
    float denom = 0.f;
    int e0 = rowptr[node], e1 = rowptr[node + 1];

    for (int p = e0; p < e1; p += U) {
        int sidx[U];
#pragma unroll
        for (int u = 0; u < U; ++u) {
            int q = p + u;
            sidx[u] = (q < e1) ? csrc[q] : -1;
        }
        half8 xlv[U];
#pragma unroll
        for (int u = 0; u < U; ++u) {
            int s = (sidx[u] >= 0) ? sidx[u] : 0;
            xlv[u] = *(const half8*)(xlg + (size_t)s * DOUT);
        }
        float part[U];
#pragma unroll
        for (int u = 0; u < U; ++u) {
            H8 t, ta;
            t.v = xlv[u] + xrh;                      // v_pk_add_f16
#pragma unroll
            for (int j = 0; j < 4; ++j) ta.u[j] = t.u[j] & 0x7fff7fffu;
            float pu = 0.f;
#pragma unroll
            for (int j = 0; j < 4; ++j) {
                pu = __builtin_amdgcn_fdot2(a6h[j], t.h2[j], pu, false);
                pu = __builtin_amdgcn_fdot2(a4h[j], ta.h2[j], pu, false);
            }
            part[u] = pu;
        }
#pragma unroll
        for (int mask = LANES / 2; mask >= 1; mask >>= 1)
#pragma unroll
            for (int u = 0; u < U; ++u)
                part[u] += __shfl_xor(part[u], mask, 64);
#pragma unroll
        for (int u = 0; u < U; ++u) {
            float w = __builtin_exp2f(part[u]);   // v_exp_f32
            w = (sidx[u] >= 0) ? w : 0.f;
            denom += w;
#pragma unroll
            for (int i = 0; i < 8; ++i)
                acc[i] += w * (float)xlv[u][i];
        }
    }
    float inv = 1.f / (denom + 1e-16f);
    const float* bp = bias + 8 * gl;
    half8 ov;
#pragma unroll
    for (int i = 0; i < 8; ++i) {
        float v = acc[i] * inv + bp[i];
        if (LEAKY) v = (v > 0.f) ? v : 0.01f * v;
        ov[i] = (_Float16)v;
    }
    *(half8*)(out + nbase) = ov;
}

// ---------------- global max pool (fp16 input, atomicMax on encoded uint) ----------------

__global__ __launch_bounds__(128) void pool_kernel(const _Float16* __restrict__ h,
        const int* __restrict__ batch, unsigned int* __restrict__ gout, int n) {
    int c0 = blockIdx.x * POOL_CHUNK;
    if (c0 >= n) return;
    int end = c0 + POOL_CHUNK; if (end > n) end = n;
    int d = threadIdx.x;  // 128
    float run = -FLT_MAX;
    int gcur = batch[c0];
    for (int nn = c0; nn < end; ++nn) {
        int g = batch[nn];
        if (g != gcur) {                       // wave-uniform branch
            atomicMax(&gout[gcur * 128 + d], enc_f32(run));
            run = -FLT_MAX;
            gcur = g;
        }
        run = fmaxf(run, (float)h[(size_t)nn * 128 + d]);
    }
    atomicMax(&gout[gcur * 128 + d], enc_f32(run));
}

// ---------------- MLP head: column x k-split parallel kernels ----------------

__global__ __launch_bounds__(256) void mlp1_kernel(const unsigned int* __restrict__ gpool,
        const float* __restrict__ w1, const float* __restrict__ b1,
        float* __restrict__ act1) {
    __shared__ float A[128];
    int g = blockIdx.x >> 2, chunk = blockIdx.x & 3;
    int t = threadIdx.x;
    if (t < 128) A[t] = dec_f32(gpool[g * 128 + t]);
    __syncthreads();
    int c = chunk * 256 + t;
    float a0 = b1[c], a1 = 0.f;
#pragma unroll 4
    for (int k = 0; k < 128; k += 2) {
        a0 += A[k] * w1[k * 1024 + c];
        a1 += A[k + 1] * w1[(k + 1) * 1024 + c];
    }
    act1[g * 1024 + c] = fmaxf(a0 + a1, 0.f);
}

template<int DIN, int DOUT>
__global__ __launch_bounds__(256) void mlp_mid_kernel(const float* __restrict__ actin,
        const float* __restrict__ w, const float* __restrict__ b,
        float* __restrict__ actout) {
    constexpr int CHUNKS = DOUT / 64;
    constexpr int KQ = DIN / 4;                 // k per split
    __shared__ float A[DIN];
    __shared__ float partial[4][64];
    int g = blockIdx.x / CHUNKS, chunk = blockIdx.x % CHUNKS;
    int t = threadIdx.x;
    for (int i = t; i < DIN; i += 256) A[i] = actin[g * DIN + i];
    __syncthreads();
    int c = chunk * 64 + (t & 63);
    int q = t >> 6;
    const float* wp = w + c + (size_t)q * KQ * DOUT;
    const float* ap = A + q * KQ;
    float a0 = 0.f, a1 = 0.f;
#pragma unroll 4
    for (int k = 0; k < KQ; k += 2) {
        a0 += ap[k] * wp[k * DOUT];
        a1 += ap[k + 1] * wp[(k + 1) * DOUT];
    }
    partial[q][t & 63] = a0 + a1;
    __syncthreads();
    if (t < 64) {
        float s = partial[0][t] + partial[1][t] + partial[2][t] + partial[3][t] + b[c];
        actout[g * DOUT + chunk * 64 + t] = fmaxf(s, 0.f);
    }
}

__global__ __launch_bounds__(128) void mlp45_kernel(const float* __restrict__ act3,
        const float* __restrict__ w4, const float* __restrict__ b4,
        const float* __restrict__ w5, const float* __restrict__ b5,
        float* __restrict__ out) {
    __shared__ float C[128], D[32];
    int g = blockIdx.x, t = threadIdx.x;
    if (t < 128) C[t] = act3[g * 128 + t];
    __syncthreads();
    if (t < 32) {
        float acc = b4[t];
#pragma unroll 4
        for (int k = 0; k < 128; ++k) acc += C[k] * w4[k * 32 + t];
        D[t] = fmaxf(acc, 0.f);
    }
    __syncthreads();
    if (t < 4) {
        float acc = b5[t];
#pragma unroll
        for (int k = 0; k < 32; ++k) acc += D[k] * w5[k * 4 + t];
        out[g * 4 + t] = acc;
    }
}

// ---------------- host launch ----------------

extern "C" void kernel_launch(void* const* d_in, const int* in_sizes, int n_in,
                              void* d_out, int out_size, void* d_ws, size_t ws_size,
                              hipStream_t stream) {
    const float* x     = (const float*)d_in[0];
    const int*   ei    = (const int*)d_in[1];
    const int*   batch = (const int*)d_in[2];
    const int*   src   = ei;
    const int*   dst   = ei + N_EDGES;
    const float* Wl1 = (const float*)d_in[3];
    const float* Wr1 = (const float*)d_in[4];
    const float* a1  = (const float*)d_in[5];
    const float* b1  = (const float*)d_in[6];
    const float* Wl2 = (const float*)d_in[7];
    const float* Wr2 = (const float*)d_in[8];
    const float* a2  = (const float*)d_in[9];
    const float* b2  = (const float*)d_in[10];
    const float* Wl3 = (const float*)d_in[11];
    const float* Wr3 = (const float*)d_in[12];
    const float* a3  = (const float*)d_in[13];
    const float* b3  = (const float*)d_in[14];
    const float* mw1 = (const float*)d_in[15];
    const float* mb1 = (const float*)d_in[16];
    const float* mw2 = (const float*)d_in[17];
    const float* mb2 = (const float*)d_in[18];
    const float* mw3 = (const float*)d_in[19];
    const float* mb3 = (const float*)d_in[20];
    const float* mw4 = (const float*)d_in[21];
    const float* mb4 = (const float*)d_in[22];
    const float* mw5 = (const float*)d_in[23];
    const float* mb5 = (const float*)d_in[24];

    char* ws = (char*)d_ws;
    size_t off = 0;
    auto alloc = [&](size_t bytes) -> void* {
        void* p = ws + off;
        off = (off + bytes + 255) & ~(size_t)255;
        return p;
    };
    // zero-init region: bhist, dhist, pool contiguous -> single memset
    int*   bhist  = (int*)alloc(NBUK * 4);
    int*   dhist  = (int*)alloc(DEG_BUCKETS * 4);
    unsigned int* pool = (unsigned int*)alloc(N_GRAPHS * 128 * 4);
    size_t zero_bytes = off;   // covers bhist..pool (0 == encoded -inf for pool)
    int*   bbase  = (int*)alloc((NBUK + 1) * 4);
    int*   bcur   = (int*)alloc(NBUK * 4);
    int*   rowptr = (int*)alloc((N_NODES + 1) * 4);
    int*   csrc   = (int*)alloc(N_EDGES * 4);
    int2*  ebuf   = (int2*)alloc((size_t)N_EDGES * 8);
    _Float16* xl  = (_Float16*)alloc((size_t)N_NODES * 128 * 2);
    _Float16* xr  = (_Float16*)alloc((size_t)N_NODES * 128 * 2);
    _Float16* hA  = (_Float16*)alloc((size_t)N_NODES * 128 * 2);
    _Float16* hB  = (_Float16*)alloc((size_t)N_NODES * 128 * 2);
    int*   dcur   = (int*)alloc(DEG_BUCKETS * 4);
    int*   perm   = (int*)alloc(N_NODES * 4);
    int*   deg    = (int*)alloc(N_NODES * 4);
    float* act1   = (float*)alloc(N_GRAPHS * 1024 * 4);
    float* act2   = (float*)alloc(N_GRAPHS * 512 * 4);
    float* act3   = (float*)alloc(N_GRAPHS * 128 * 4);

    hipMemsetAsync(bhist, 0, zero_bytes, stream);
    bucket_hist_kernel<<<(N_EDGES + 1023) / 1024, 256, 0, stream>>>(dst, bhist, N_EDGES);
    bucket_scan_kernel<<<1, 256, 0, stream>>>(bhist, bbase, bcur);
    binscat_kernel<<<(N_EDGES + CHUNK - 1) / CHUNK, 256, 0, stream>>>(src, dst, bcur, ebuf, N_EDGES);
    csr_final_kernel<<<NBUK, 256, 0, stream>>>(ebuf, bbase, rowptr, csrc, deg, dhist, N_NODES, N_EDGES);
    dscan_kernel<<<1, 64, 0, stream>>>(dhist, dcur);
    perm_kernel<<<SCAN_NB, 256, 0, stream>>>(deg, dcur, perm, N_NODES);

    auto egrid = [](int npw) {
        int waves = (N_NODES + npw - 1) / npw;
        return (waves + 3) / 4;
    };
    const int gblocks = (N_NODES + 63) / 64;   // 782

    // Layer 1: 128 -> 32 (MFMA dual GEMM, f32 in); edge NPW=16 (LANES=4), U=16, fp16 out
    mfma_gemm_kernel<float, 128, 32><<<gblocks, 256, 0, stream>>>(x, Wl1, Wr1, xl, xr, N_NODES);
    edge_kernel<32, 16, true><<<egrid(16), 256, 0, stream>>>(xl, xr, a1, b1, rowptr, csrc, perm, hB, N_NODES);
    // Layer 2: 32 -> 64 (MFMA, f16 in); edge NPW=8 (LANES=8), U=16, fp16 out
    mfma_gemm_kernel<_Float16, 32, 64><<<gblocks, 256, 0, stream>>>(hB, Wl2, Wr2, xl, xr, N_NODES);
    edge_kernel<64, 16, true><<<egrid(8), 256, 0, stream>>>(xl, xr, a2, b2, rowptr, csrc, perm, hA, N_NODES);
    // Layer 3: 64 -> 128 (MFMA, f16 in); edge NPW=4 (LANES=16), U=8, fp16 out
    mfma_gemm_kernel<_Float16, 64, 128><<<gblocks, 256, 0, stream>>>(hA, Wl3, Wr3, xl, xr, N_NODES);
    edge_kernel<128, 8, false><<<egrid(4), 256, 0, stream>>>(xl, xr, a3, b3, rowptr, csrc, perm, hB, N_NODES);

    pool_kernel<<<(N_NODES + POOL_CHUNK - 1) / POOL_CHUNK, 128, 0, stream>>>(hB, batch, pool, N_NODES);
    mlp1_kernel<<<N_GRAPHS * 4, 256, 0, stream>>>(pool, mw1, mb1, act1);
    mlp_mid_kernel<1024, 512><<<N_GRAPHS * 8, 256, 0, stream>>>(act1, mw2, mb2, act2);
    mlp_mid_kernel<512, 128><<<N_GRAPHS * 2, 256, 0, stream>>>(act2, mw3, mb3, act3);
    mlp45_kernel<<<N_GRAPHS, 128, 0, stream>>>(act3, mw4, mb4, mw5, mb5, (float*)d_out);
}

// Round 8
// 328.732 us; speedup vs baseline: 1.6411x; 1.0163x over previous
//
#include <hip/hip_runtime.h>
#include <cfloat>

#define N_NODES 50000
#define N_EDGES 800000
#define N_GRAPHS 64
#define POOL_CHUNK 64
#define DEG_BUCKETS 64
#define SCAN_NB ((N_NODES + 255) / 256)   // 196

// CSR binning parameters
#define BUK_SHIFT 8                        // 256 nodes per bucket
#define NBUK ((N_NODES + 255) / 256)       // 196 buckets
#define CHUNK 4096                         // edges per binscat block
#define CAP 6144                           // LDS csrc staging capacity (mean region = 4096)

typedef _Float16 half8 __attribute__((ext_vector_type(8)));
typedef _Float16 half4 __attribute__((ext_vector_type(4)));
typedef _Float16 half2t __attribute__((ext_vector_type(2)));
typedef _Float16 f16x8 __attribute__((ext_vector_type(8)));
typedef float f32x4 __attribute__((ext_vector_type(4)));
typedef float f32x2 __attribute__((ext_vector_type(2)));

// ---------------- CSR build: bucket histogram ----------------

__global__ __launch_bounds__(256) void bucket_hist_kernel(const int* __restrict__ dst,
                                                          int* __restrict__ bhist, int n) {
    __shared__ int lh[NBUK];
    int t = threadIdx.x;
    if (t < NBUK) lh[t] = 0;
    __syncthreads();
    int i0 = blockIdx.x * 1024;
#pragma unroll
    for (int j = 0; j < 4; ++j) {
        int i = i0 + j * 256 + t;
        if (i < n) atomicAdd(&lh[dst[i] >> BUK_SHIFT], 1);
    }
    __syncthreads();
    if (t < NBUK && lh[t]) atomicAdd(&bhist[t], lh[t]);
}

// single block: scan 196 bucket counts -> bbase (exclusive, +total), init bcur
__global__ __launch_bounds__(256) void bucket_scan_kernel(const int* __restrict__ bhist,
                                                          int* __restrict__ bbase,
                                                          int* __restrict__ bcur) {
    __shared__ int sm[256];
    int t = threadIdx.x;
    int v = (t < NBUK) ? bhist[t] : 0;
    sm[t] = v;
    __syncthreads();
    for (int off = 1; off < 256; off <<= 1) {
        int x = (t >= off) ? sm[t - off] : 0;
        __syncthreads();
        sm[t] += x;
        __syncthreads();
    }
    int excl = sm[t] - v;
    if (t < NBUK) { bbase[t] = excl; bcur[t] = excl; }
    if (t == 255) bbase[NBUK] = sm[255];
}

// ---------------- binscat: LDS-staged bucket append (coalesced flushes) ----------------
// ebuf entry packed: src in bits [0,24), dst-local (dst & 255) in bits [24,32).

__global__ __launch_bounds__(256) void binscat_kernel(const int* __restrict__ src,
        const int* __restrict__ dst, int* __restrict__ bcur,
        unsigned int* __restrict__ ebuf, int n) {
    __shared__ int2 staged[CHUNK];
    __shared__ int lh[NBUK], lbase[NBUK], lpos[NBUK], gpos[NBUK];
    __shared__ int ssc[256];
    int t = threadIdx.x;
    int e0 = blockIdx.x * CHUNK;
    int len = n - e0; if (len > CHUNK) len = CHUNK; if (len < 0) len = 0;
    if (t < NBUK) { lh[t] = 0; lpos[t] = 0; }
    __syncthreads();
    int s[16], d[16];
#pragma unroll
    for (int j = 0; j < 16; ++j) {
        int i = j * 256 + t;
        if (i < len) {
            s[j] = src[e0 + i];
            d[j] = dst[e0 + i];
            atomicAdd(&lh[d[j] >> BUK_SHIFT], 1);
        } else d[j] = -1;
    }
    __syncthreads();
    // block scan of lh (NBUK <= 256)
    int v = (t < NBUK) ? lh[t] : 0;
    ssc[t] = v;
    __syncthreads();
    for (int off = 1; off < 256; off <<= 1) {
        int x = (t >= off) ? ssc[t - off] : 0;
        __syncthreads();
        ssc[t] += x;
        __syncthreads();
    }
    if (t < NBUK) {
        lbase[t] = ssc[t] - v;
        gpos[t] = v ? atomicAdd(&bcur[t], v) : 0;
    }
    __syncthreads();
#pragma unroll
    for (int j = 0; j < 16; ++j) {
        if (d[j] >= 0) {
            int b = d[j] >> BUK_SHIFT;
            int slot = lbase[b] + atomicAdd(&lpos[b], 1);
            staged[slot] = make_int2(s[j], d[j]);
        }
    }
    __syncthreads();
    // flush: bucket segments are contiguous in staged AND in ebuf -> coalesced runs
    for (int i = t; i < len; i += 256) {
        int2 p = staged[i];
        int b = p.y >> BUK_SHIFT;
        unsigned int pk = (unsigned int)p.x | ((unsigned int)(p.y & 255) << 24);
        ebuf[gpos[b] + (i - lbase[b])] = pk;
    }
}

// ---------------- csr_final: per-bucket CSR segment in LDS, coalesced out ----------------
// Emits rowptr, csrc, deg, and degree-histogram (for LPT perm).

__global__ __launch_bounds__(256) void csr_final_kernel(const unsigned int* __restrict__ ebuf,
        const int* __restrict__ bbase, int* __restrict__ rowptr, int* __restrict__ csrc,
        int* __restrict__ deg, int* __restrict__ dhist, int n_nodes, int n_edges) {
    __shared__ int lcnt[256], lbs[256], lpos[256], ssc[256];
    __shared__ int lh64[DEG_BUCKETS];
    __shared__ int buf[CAP];
    int b = blockIdx.x, t = threadIdx.x;
    int nstart = b << BUK_SHIFT;
    int nodes = n_nodes - nstart; if (nodes > 256) nodes = 256;
    int r0 = bbase[b], r1 = bbase[b + 1];
    int len = r1 - r0;
    lcnt[t] = 0;
    lpos[t] = 0;
    if (t < DEG_BUCKETS) lh64[t] = 0;
    __syncthreads();
    for (int i = t; i < len; i += 256)
        atomicAdd(&lcnt[ebuf[r0 + i] >> 24], 1);
    __syncthreads();
    int v = lcnt[t];
    ssc[t] = v;
    __syncthreads();
    for (int off = 1; off < 256; off <<= 1) {
        int x = (t >= off) ? ssc[t - off] : 0;
        __syncthreads();
        ssc[t] += x;
        __syncthreads();
    }
    lbs[t] = ssc[t] - v;                      // exclusive local base
    if (t < nodes) {
        rowptr[nstart + t] = r0 + lbs[t];
        deg[nstart + t] = v;
        int dd = (v > DEG_BUCKETS - 1) ? DEG_BUCKETS - 1 : v;
        atomicAdd(&lh64[dd], 1);
    }
    if (b == NBUK - 1 && t == 0) rowptr[n_nodes] = n_edges;
    __syncthreads();
    if (t < DEG_BUCKETS && lh64[t]) atomicAdd(&dhist[t], lh64[t]);
    if (len <= CAP) {
        for (int i = t; i < len; i += 256) {
            unsigned int p = ebuf[r0 + i];
            int dn = p >> 24;
            int pos = lbs[dn] + atomicAdd(&lpos[dn], 1);
            buf[pos] = (int)(p & 0xFFFFFFu);
        }
        __syncthreads();
        for (int i = t; i < len; i += 256) csrc[r0 + i] = buf[i];
    } else {
        // freak-bucket fallback: direct global scatter (correct, slower)
        for (int i = t; i < len; i += 256) {
            unsigned int p = ebuf[r0 + i];
            int dn = p >> 24;
            int pos = lbs[dn] + atomicAdd(&lpos[dn], 1);
            csrc[r0 + pos] = (int)(p & 0xFFFFFFu);
        }
    }
}

// ---------------- degree-bucket scan + LPT perm ----------------

__global__ void dscan_kernel(const int* __restrict__ dhist, int* __restrict__ dcur) {
    int t = threadIdx.x;  // 64
    int dv = dhist[t];
    int incl = dv;
    for (int off = 1; off < 64; off <<= 1) {
        int x = __shfl_up(incl, off, 64);
        if (t >= off) incl += x;
    }
    dcur[t] = incl - dv;
}

__global__ __launch_bounds__(256) void perm_kernel(const int* __restrict__ deg,
        int* __restrict__ dcur, int* __restrict__ perm, int n) {
    __shared__ int lh[DEG_BUCKETS], lbase[DEG_BUCKETS];
    int t = threadIdx.x;
    int i = blockIdx.x * 256 + t;
    if (t < DEG_BUCKETS) lh[t] = 0;
    __syncthreads();
    int d = 0, loc = 0;
    bool valid = (i < n);
    if (valid) {
        int v = deg[i];
        d = (v > DEG_BUCKETS - 1) ? DEG_BUCKETS - 1 : v;
        loc = atomicAdd(&lh[d], 1);
    }
    __syncthreads();
    if (t < DEG_BUCKETS) lbase[t] = lh[t] ? atomicAdd(&dcur[t], lh[t]) : 0;
    __syncthreads();
    if (valid) perm[lbase[d] + loc] = i;
}

// ---------------- MFMA dual GEMM: [xl|xr] = h @ [Wl|Wr], fp16 out, f32/f16 in ----------------

template<typename TIN, int DIN, int DOUT>
__global__ __launch_bounds__(256) void mfma_gemm_kernel(const TIN* __restrict__ h,
        const float* __restrict__ Wl, const float* __restrict__ Wr,
        _Float16* __restrict__ xl, _Float16* __restrict__ xr, int n) {
    constexpr int NOUT = 2 * DOUT;
    constexpr int BM = 64;
    constexpr int NCH = DIN / 8;                      // 16B chunks per LDS row
    constexpr int XORM = (NCH < 8 ? NCH : 8) - 1;
    constexpr int NT = NOUT / 16;
    static_assert(DIN % 32 == 0 && DOUT % 16 == 0, "shape");
    __shared__ _Float16 sA[BM * DIN];
    __shared__ _Float16 sW[NOUT * DIN];               // W^T: [n][k]
    int tid = threadIdx.x;
    int r0 = blockIdx.x * BM;

    // stage W^T fp16 (swizzled); W is [DIN][DOUT] row-major fp32
    for (int i = tid; i < DIN * DOUT; i += 256) {
        int k = i / DOUT, c = i % DOUT;
        sW[c * DIN + (k ^ ((c & XORM) << 3))] = (_Float16)Wl[i];
        int nr = DOUT + c;
        sW[nr * DIN + (k ^ ((nr & XORM) << 3))] = (_Float16)Wr[i];
    }
    // stage A fp16 (swizzled)
    if constexpr (sizeof(TIN) == 4) {
        constexpr int DQ = DIN / 4;
        for (int i = tid; i < BM * DQ; i += 256) {
            int row = i / DQ, kq = (i % DQ) * 4;
            float4 v = (r0 + row < n) ? *(const float4*)(h + (size_t)(r0 + row) * DIN + kq)
                                      : make_float4(0.f, 0.f, 0.f, 0.f);
            half4 hv = {(_Float16)v.x, (_Float16)v.y, (_Float16)v.z, (_Float16)v.w};
            *(half4*)(sA + row * DIN + (kq ^ ((row & XORM) << 3))) = hv;
        }
    } else {
        constexpr int D8 = DIN / 8;
        for (int i = tid; i < BM * D8; i += 256) {
            int row = i / D8, k8 = (i % D8) * 8;
            half8 hv;
            if (r0 + row < n) hv = *(const half8*)(h + (size_t)(r0 + row) * DIN + k8);
            else hv = half8{0, 0, 0, 0, 0, 0, 0, 0};
            *(half8*)(sA + row * DIN + (k8 ^ ((row & XORM) << 3))) = hv;
        }
    }
    __syncthreads();

    int w = tid >> 6, lane = tid & 63;
    int lrow = lane & 15, lg = lane >> 4;
    int arow = w * 16 + lrow;

    f32x4 acc[NT];
#pragma unroll
    for (int i = 0; i < NT; ++i) acc[i] = (f32x4){0.f, 0.f, 0.f, 0.f};

#pragma unroll
    for (int kk = 0; kk < DIN; kk += 32) {
        int ka = kk + lg * 8;
        f16x8 af = *(const f16x8*)(sA + arow * DIN + (ka ^ ((arow & XORM) << 3)));
#pragma unroll
        for (int nt = 0; nt < NT; ++nt) {
            int bcol = nt * 16 + lrow;
            f16x8 bf = *(const f16x8*)(sW + bcol * DIN + (ka ^ ((bcol & XORM) << 3)));
            acc[nt] = __builtin_amdgcn_mfma_f32_16x16x32_f16(af, bf, acc[nt], 0, 0, 0);
        }
    }

    int orow0 = r0 + w * 16 + lg * 4;
#pragma unroll
    for (int nt = 0; nt < NT; ++nt) {
        int c = nt * 16 + lrow;
        _Float16* obase = (c < DOUT) ? xl : xr;
        int cc = (c < DOUT) ? c : c - DOUT;
#pragma unroll
        for (int r = 0; r < 4; ++r) {
            int row = orow0 + r;
            if (row < n) obase[(size_t)row * DOUT + cc] = (_Float16)acc[nt][r];
        }
    }
}

// ---------------- fused per-node GATv2 softmax-aggregate (fp16, packed dot2) ----------------
// Score path in packed fp16: t = xl+xr via v_pk_add_f16, |t| via bit-mask,
// attention dot via v_dot2_f32_f16 (f32 accumulate). Aggregation f32 but
// packed as float2 -> v_pk_fma_f32. Output row stored fp16.

union H8 {
    half8 v;
    half2t h2[4];
    unsigned int u[4];
};

__device__ __forceinline__ unsigned int enc_f32(float f) {
    unsigned int b = __float_as_uint(f);
    return (b & 0x80000000u) ? ~b : (b | 0x80000000u);
}
__device__ __forceinline__ float dec_f32(unsigned int u) {
    unsigned int b = (u & 0x80000000u) ? (u ^ 0x80000000u) : ~u;
    return __uint_as_float(b);
}

template<int DOUT, int U, bool LEAKY>
__global__ __launch_bounds__(256) void edge_kernel(
        const _Float16* __restrict__ xl, const _Float16* __restrict__ xr,
        const float* __restrict__ avec, const float* __restrict__ bias,
        const int* __restrict__ rowptr, const int* __restrict__ csrc,
        const int* __restrict__ perm,
        _Float16* __restrict__ out, int n) {
    constexpr int LANES = DOUT / 8;              // 4 / 8 / 16
    constexpr int NPW = 64 / LANES;              // nodes per wave
    int wid = (blockIdx.x * blockDim.x + threadIdx.x) >> 6;
    int lane = threadIdx.x & 63;
    int group = lane / LANES;
    int gl = lane % LANES;
    int gnode = wid * NPW + group;
    if (gnode >= n) return;
    int node = perm[n - 1 - gnode];              // descending degree (LPT)

    constexpr float L2E = 1.44269504f;
    const float* ap = avec + 8 * gl;
    half2t a6h[4], a4h[4];
#pragma unroll
    for (int j = 0; j < 4; ++j) {
        float x0 = 0.6f * L2E * ap[2 * j], x1 = 0.6f * L2E * ap[2 * j + 1];
        a6h[j] = half2t{(_Float16)x0, (_Float16)x1};
        float y0 = 0.4f * L2E * ap[2 * j], y1 = 0.4f * L2E * ap[2 * j + 1];
        a4h[j] = half2t{(_Float16)y0, (_Float16)y1};
    }

    int nbase = node * DOUT + 8 * gl;
    half8 xrh = *(const half8*)(xr + nbase);
    const _Float16* xlg = xl + 8 * gl;

    f32x2 acc2[4] = {};
    float denom = 0.f;
    int e0 = rowptr[node], e1 = rowptr[node + 1];

    for (int p = e0; p < e1; p += U) {
        int sidx[U];
#pragma unroll
        for (int u = 0; u < U; ++u) {
            int q = p + u;
            sidx[u] = (q < e1) ? csrc[q] : -1;
        }
        half8 xlv[U];
#pragma unroll
        for (int u = 0; u < U; ++u) {
            int s = (sidx[u] >= 0) ? sidx[u] : 0;
            xlv[u] = *(const half8*)(xlg + (size_t)s * DOUT);
        }
        float part[U];
#pragma unroll
        for (int u = 0; u < U; ++u) {
            H8 t, ta;
            t.v = xlv[u] + xrh;                      // v_pk_add_f16
#pragma unroll
            for (int j = 0; j < 4; ++j) ta.u[j] = t.u[j] & 0x7fff7fffu;
            float pu = 0.f;
#pragma unroll
            for (int j = 0; j < 4; ++j) {
                pu = __builtin_amdgcn_fdot2(a6h[j], t.h2[j], pu, false);
                pu = __builtin_amdgcn_fdot2(a4h[j], ta.h2[j], pu, false);
            }
            part[u] = pu;
        }
#pragma unroll
        for (int mask = LANES / 2; mask >= 1; mask >>= 1)
#pragma unroll
            for (int u = 0; u < U; ++u)
                part[u] += __shfl_xor(part[u], mask, 64);
#pragma unroll
        for (int u = 0; u < U; ++u) {
            float w = __builtin_exp2f(part[u]);   // v_exp_f32
            w = (sidx[u] >= 0) ? w : 0.f;
            denom += w;
            f32x2 wv = {w, w};
#pragma unroll
            for (int j = 0; j < 4; ++j) {
                f32x2 xf = {(float)xlv[u][2 * j], (float)xlv[u][2 * j + 1]};
                acc2[j] += wv * xf;                  // v_pk_fma_f32
            }
        }
    }
    float inv = 1.f / (denom + 1e-16f);
    const float* bp = bias + 8 * gl;
    half8 ov;
#pragma unroll
    for (int i = 0; i < 8; ++i) {
        float v = acc2[i >> 1][i & 1] * inv + bp[i];
        if (LEAKY) v = (v > 0.f) ? v : 0.01f * v;
        ov[i] = (_Float16)v;
    }
    *(half8*)(out + nbase) = ov;
}

// ---------------- global max pool (fp16 input, atomicMax on encoded uint) ----------------

__global__ __launch_bounds__(128) void pool_kernel(const _Float16* __restrict__ h,
        const int* __restrict__ batch, unsigned int* __restrict__ gout, int n) {
    int c0 = blockIdx.x * POOL_CHUNK;
    if (c0 >= n) return;
    int end = c0 + POOL_CHUNK; if (end > n) end = n;
    int d = threadIdx.x;  // 128
    float run = -FLT_MAX;
    int gcur = batch[c0];
    for (int nn = c0; nn < end; ++nn) {
        int g = batch[nn];
        if (g != gcur) {                       // wave-uniform branch
            atomicMax(&gout[gcur * 128 + d], enc_f32(run));
            run = -FLT_MAX;
            gcur = g;
        }
        run = fmaxf(run, (float)h[(size_t)nn * 128 + d]);
    }
    atomicMax(&gout[gcur * 128 + d], enc_f32(run));
}

// ---------------- MLP head: column x k-split parallel kernels ----------------

__global__ __launch_bounds__(256) void mlp1_kernel(const unsigned int* __restrict__ gpool,
        const float* __restrict__ w1, const float* __restrict__ b1,
        float* __restrict__ act1) {
    __shared__ float A[128];
    int g = blockIdx.x >> 2, chunk = blockIdx.x & 3;
    int t = threadIdx.x;
    if (t < 128) A[t] = dec_f32(gpool[g * 128 + t]);
    __syncthreads();
    int c = chunk * 256 + t;
    float a0 = b1[c], a1 = 0.f;
#pragma unroll 4
    for (int k = 0; k < 128; k += 2) {
        a0 += A[k] * w1[k * 1024 + c];
        a1 += A[k + 1] * w1[(k + 1) * 1024 + c];
    }
    act1[g * 1024 + c] = fmaxf(a0 + a1, 0.f);
}

template<int DIN, int DOUT>
__global__ __launch_bounds__(256) void mlp_mid_kernel(const float* __restrict__ actin,
        const float* __restrict__ w, const float* __restrict__ b,
        float* __restrict__ actout) {
    constexpr int CHUNKS = DOUT / 64;
    constexpr int KQ = DIN / 4;                 // k per split
    __shared__ float A[DIN];
    __shared__ float partial[4][64];
    int g = blockIdx.x / CHUNKS, chunk = blockIdx.x % CHUNKS;
    int t = threadIdx.x;
    for (int i = t; i < DIN; i += 256) A[i] = actin[g * DIN + i];
    __syncthreads();
    int c = chunk * 64 + (t & 63);
    int q = t >> 6;
    const float* wp = w + c + (size_t)q * KQ * DOUT;
    const float* ap = A + q * KQ;
    float a0 = 0.f, a1 = 0.f;
#pragma unroll 4
    for (int k = 0; k < KQ; k += 2) {
        a0 += ap[k] * wp[k * DOUT];
        a1 += ap[k + 1] * wp[(k + 1) * DOUT];
    }
    partial[q][t & 63] = a0 + a1;
    __syncthreads();
    if (t < 64) {
        float s = partial[0][t] + partial[1][t] + partial[2][t] + partial[3][t] + b[c];
        actout[g * DOUT + chunk * 64 + t] = fmaxf(s, 0.f);
    }
}

__global__ __launch_bounds__(128) void mlp45_kernel(const float* __restrict__ act3,
        const float* __restrict__ w4, const float* __restrict__ b4,
        const float* __restrict__ w5, const float* __restrict__ b5,
        float* __restrict__ out) {
    __shared__ float C[128], D[32];
    int g = blockIdx.x, t = threadIdx.x;
    if (t < 128) C[t] = act3[g * 128 + t];
    __syncthreads();
    if (t < 32) {
        float acc = b4[t];
#pragma unroll 4
        for (int k = 0; k < 128; ++k) acc += C[k] * w4[k * 32 + t];
        D[t] = fmaxf(acc, 0.f);
    }
    __syncthreads();
    if (t < 4) {
        float acc = b5[t];
#pragma unroll
        for (int k = 0; k < 32; ++k) acc += D[k] * w5[k * 4 + t];
        out[g * 4 + t] = acc;
    }
}

// ---------------- host launch ----------------

extern "C" void kernel_launch(void* const* d_in, const int* in_sizes, int n_in,
                              void* d_out, int out_size, void* d_ws, size_t ws_size,
                              hipStream_t stream) {
    const float* x     = (const float*)d_in[0];
    const int*   ei    = (const int*)d_in[1];
    const int*   batch = (const int*)d_in[2];
    const int*   src   = ei;
    const int*   dst   = ei + N_EDGES;
    const float* Wl1 = (const float*)d_in[3];
    const float* Wr1 = (const float*)d_in[4];
    const float* a1  = (const float*)d_in[5];
    const float* b1  = (const float*)d_in[6];
    const float* Wl2 = (const float*)d_in[7];
    const float* Wr2 = (const float*)d_in[8];
    const float* a2  = (const float*)d_in[9];
    const float* b2  = (const float*)d_in[10];
    const float* Wl3 = (const float*)d_in[11];
    const float* Wr3 = (const float*)d_in[12];
    const float* a3  = (const float*)d_in[13];
    const float* b3  = (const float*)d_in[14];
    const float* mw1 = (const float*)d_in[15];
    const float* mb1 = (const float*)d_in[16];
    const float* mw2 = (const float*)d_in[17];
    const float* mb2 = (const float*)d_in[18];
    const float* mw3 = (const float*)d_in[19];
    const float* mb3 = (const float*)d_in[20];
    const float* mw4 = (const float*)d_in[21];
    const float* mb4 = (const float*)d_in[22];
    const float* mw5 = (const float*)d_in[23];
    const float* mb5 = (const float*)d_in[24];

    char* ws = (char*)d_ws;
    size_t off = 0;
    auto alloc = [&](size_t bytes) -> void* {
        void* p = ws + off;
        off = (off + bytes + 255) & ~(size_t)255;
        return p;
    };
    // zero-init region: bhist, dhist, pool contiguous -> single memset
    int*   bhist  = (int*)alloc(NBUK * 4);
    int*   dhist  = (int*)alloc(DEG_BUCKETS * 4);
    unsigned int* pool = (unsigned int*)alloc(N_GRAPHS * 128 * 4);
    size_t zero_bytes = off;   // covers bhist..pool (0 == encoded -inf for pool)
    int*   bbase  = (int*)alloc((NBUK + 1) * 4);
    int*   bcur   = (int*)alloc(NBUK * 4);
    int*   rowptr = (int*)alloc((N_NODES + 1) * 4);
    int*   csrc   = (int*)alloc(N_EDGES * 4);
    unsigned int* ebuf = (unsigned int*)alloc((size_t)N_EDGES * 4);
    _Float16* xl  = (_Float16*)alloc((size_t)N_NODES * 128 * 2);
    _Float16* xr  = (_Float16*)alloc((size_t)N_NODES * 128 * 2);
    _Float16* hA  = (_Float16*)alloc((size_t)N_NODES * 128 * 2);
    _Float16* hB  = (_Float16*)alloc((size_t)N_NODES * 128 * 2);
    int*   dcur   = (int*)alloc(DEG_BUCKETS * 4);
    int*   perm   = (int*)alloc(N_NODES * 4);
    int*   deg    = (int*)alloc(N_NODES * 4);
    float* act1   = (float*)alloc(N_GRAPHS * 1024 * 4);
    float* act2   = (float*)alloc(N_GRAPHS * 512 * 4);
    float* act3   = (float*)alloc(N_GRAPHS * 128 * 4);

    hipMemsetAsync(bhist, 0, zero_bytes, stream);
    bucket_hist_kernel<<<(N_EDGES + 1023) / 1024, 256, 0, stream>>>(dst, bhist, N_EDGES);
    bucket_scan_kernel<<<1, 256, 0, stream>>>(bhist, bbase, bcur);
    binscat_kernel<<<(N_EDGES + CHUNK - 1) / CHUNK, 256, 0, stream>>>(src, dst, bcur, ebuf, N_EDGES);
    csr_final_kernel<<<NBUK, 256, 0, stream>>>(ebuf, bbase, rowptr, csrc, deg, dhist, N_NODES, N_EDGES);
    dscan_kernel<<<1, 64, 0, stream>>>(dhist, dcur);
    perm_kernel<<<SCAN_NB, 256, 0, stream>>>(deg, dcur, perm, N_NODES);

    auto egrid = [](int npw) {
        int waves = (N_NODES + npw - 1) / npw;
        return (waves + 3) / 4;
    };
    const int gblocks = (N_NODES + 63) / 64;   // 782

    // Layer 1: 128 -> 32 (MFMA dual GEMM, f32 in); edge NPW=16 (LANES=4), U=16, fp16 out
    mfma_gemm_kernel<float, 128, 32><<<gblocks, 256, 0, stream>>>(x, Wl1, Wr1, xl, xr, N_NODES);
    edge_kernel<32, 16, true><<<egrid(16), 256, 0, stream>>>(xl, xr, a1, b1, rowptr, csrc, perm, hB, N_NODES);
    // Layer 2: 32 -> 64 (MFMA, f16 in); edge NPW=8 (LANES=8), U=16, fp16 out
    mfma_gemm_kernel<_Float16, 32, 64><<<gblocks, 256, 0, stream>>>(hB, Wl2, Wr2, xl, xr, N_NODES);
    edge_kernel<64, 16, true><<<egrid(8), 256, 0, stream>>>(xl, xr, a2, b2, rowptr, csrc, perm, hA, N_NODES);
    // Layer 3: 64 -> 128 (MFMA, f16 in); edge NPW=4 (LANES=16), U=8, fp16 out
    mfma_gemm_kernel<_Float16, 64, 128><<<gblocks, 256, 0, stream>>>(hA, Wl3, Wr3, xl, xr, N_NODES);
    edge_kernel<128, 8, false><<<egrid(4), 256, 0, stream>>>(xl, xr, a3, b3, rowptr, csrc, perm, hB, N_NODES);

    pool_kernel<<<(N_NODES + POOL_CHUNK - 1) / POOL_CHUNK, 128, 0, stream>>>(hB, batch, pool, N_NODES);
    mlp1_kernel<<<N_GRAPHS * 4, 256, 0, stream>>>(pool, mw1, mb1, act1);
    mlp_mid_kernel<1024, 512><<<N_GRAPHS * 8, 256, 0, stream>>>(act1, mw2, mb2, act2);
    mlp_mid_kernel<512, 128><<<N_GRAPHS * 2, 256, 0, stream>>>(act2, mw3, mb3, act3);
    mlp45_kernel<<<N_GRAPHS, 128, 0, stream>>>(act3, mw4, mb4, mw5, mb5, (float*)d_out);
}